// Round 5
// baseline (3393.154 us; speedup 1.0000x reference)
//
#include <hip/hip_runtime.h>

// SNN: two recurrent LIF layers + linear readout.
// B=256, T=100, F=256, H=1024, O=8. All fp32.
//
// Round 6:
//   - lif_scan: slist stores PRE-SHIFTED byte offsets (k<<12); gather address
//     is a single v_or with precomputed tid*4 -> ~2 VALU/row (or + add).
//     Gather order unchanged -> bit-exact. Scan is ~7% above the L2 roofline
//     (n~370 rows x 4KB x 256 blocks / 36.9 TB/s ~= 10.6 us/step).
//   - gemm_f32: BK=16 (halves barriers vs round-5), 128x128 tile, 8x8 micro,
//     double-buffered LDS. Ascending-k single fmaf chain per output -> exact.
//   - readout_gemm: thread-per-row, 8 accumulators, uniform (scalar) Wout
//     loads; s2 row read once instead of 8x. Same per-output chain -> exact.

#define SNN_B 256
#define SNN_T 100
#define SNN_F 256
#define SNN_H 1024
#define SNN_O 8

#define ALPHA 0.9048374180359595f  // exp(-0.1)
#define BETA  0.8187307530779818f  // exp(-0.2)

// ---------------------------------------------------------------------------
// fp32 GEMM: C[M,N] = A[M,K] @ B[K,N], row-major. 128x128 tile, BK=16,
// 256 threads, 8x8 micro-tile, double-buffered LDS.
// Per-output accumulation: single fmaf chain over ascending k -> bit-identical.
// Requires M%128==0, N%128==0, K%16==0.
// ---------------------------------------------------------------------------
__global__ __launch_bounds__(256) void gemm_f32(
    const float* __restrict__ A, const float* __restrict__ Bm,
    float* __restrict__ C, int M, int N, int K)
{
    __shared__ float As[2][16][132];   // [buf][k][m], padded
    __shared__ float Bs[2][16][132];   // [buf][k][n], padded

    const int tid = threadIdx.x;
    const int m0 = blockIdx.y * 128;
    const int n0 = blockIdx.x * 128;
    const int ty = tid >> 4;           // 0..15 -> rows ty*8..+7
    const int tx = tid & 15;           // 0..15 -> cols tx*8..+7

    // staging: A tile 128x16 = 512 float4 (2/thread), B tile 16x128 = 512 (2/thread)
    const int arow = tid >> 1;          // 0..127
    const int ak0  = (tid & 1) * 4;     // k offsets ak0 and ak0+8
    const int bk0  = tid >> 5;          // rows bk0 and bk0+8
    const int bnq  = (tid & 31) * 4;    // 0..124

    const float* Aptr = A + (size_t)(m0 + arow) * K;
    const float* Bptr = Bm + n0 + bnq;

    // prologue: stage k-tile 0 into buffer 0
    float4 a0r = *(const float4*)(Aptr + ak0);
    float4 a1r = *(const float4*)(Aptr + ak0 + 8);
    float4 b0r = *(const float4*)(Bptr + (size_t)bk0 * N);
    float4 b1r = *(const float4*)(Bptr + (size_t)(bk0 + 8) * N);
    As[0][ak0 + 0][arow] = a0r.x;
    As[0][ak0 + 1][arow] = a0r.y;
    As[0][ak0 + 2][arow] = a0r.z;
    As[0][ak0 + 3][arow] = a0r.w;
    As[0][ak0 + 8][arow] = a1r.x;
    As[0][ak0 + 9][arow] = a1r.y;
    As[0][ak0 + 10][arow] = a1r.z;
    As[0][ak0 + 11][arow] = a1r.w;
    *(float4*)&Bs[0][bk0][bnq] = b0r;
    *(float4*)&Bs[0][bk0 + 8][bnq] = b1r;
    __syncthreads();

    float acc[8][8] = {};
    const int NK = K >> 4;

    for (int kt = 0; kt < NK; ++kt) {
        const int cur = kt & 1;
        if (kt + 1 < NK) {               // issue next tile's loads early
            const float* Ap = Aptr + (kt + 1) * 16;
            const float* Bp = Bptr + (size_t)(kt + 1) * 16 * N;
            a0r = *(const float4*)(Ap + ak0);
            a1r = *(const float4*)(Ap + ak0 + 8);
            b0r = *(const float4*)(Bp + (size_t)bk0 * N);
            b1r = *(const float4*)(Bp + (size_t)(bk0 + 8) * N);
        }
        #pragma unroll
        for (int k = 0; k < 16; ++k) {
            const float4 av0 = *(const float4*)&As[cur][k][ty * 8];
            const float4 av1 = *(const float4*)&As[cur][k][ty * 8 + 4];
            const float4 bv0 = *(const float4*)&Bs[cur][k][tx * 8];
            const float4 bv1 = *(const float4*)&Bs[cur][k][tx * 8 + 4];
            const float am[8] = {av0.x, av0.y, av0.z, av0.w, av1.x, av1.y, av1.z, av1.w};
            const float bn[8] = {bv0.x, bv0.y, bv0.z, bv0.w, bv1.x, bv1.y, bv1.z, bv1.w};
            #pragma unroll
            for (int i = 0; i < 8; ++i)
                #pragma unroll
                for (int j = 0; j < 8; ++j)
                    acc[i][j] = fmaf(am[i], bn[j], acc[i][j]);
        }
        if (kt + 1 < NK) {
            const int nxt = cur ^ 1;
            __syncthreads();             // prior reads of buffer nxt complete
            As[nxt][ak0 + 0][arow] = a0r.x;
            As[nxt][ak0 + 1][arow] = a0r.y;
            As[nxt][ak0 + 2][arow] = a0r.z;
            As[nxt][ak0 + 3][arow] = a0r.w;
            As[nxt][ak0 + 8][arow] = a1r.x;
            As[nxt][ak0 + 9][arow] = a1r.y;
            As[nxt][ak0 + 10][arow] = a1r.z;
            As[nxt][ak0 + 11][arow] = a1r.w;
            *(float4*)&Bs[nxt][bk0][bnq] = b0r;
            *(float4*)&Bs[nxt][bk0 + 8][bnq] = b1r;
            __syncthreads();             // writes visible before next compute
        }
    }

    #pragma unroll
    for (int i = 0; i < 8; ++i) {
        float* crow = C + (size_t)(m0 + ty * 8 + i) * N + n0 + tx * 8;
        *(float4*)crow = make_float4(acc[i][0], acc[i][1], acc[i][2], acc[i][3]);
        *(float4*)(crow + 4) = make_float4(acc[i][4], acc[i][5], acc[i][6], acc[i][7]);
    }
}

// ---------------------------------------------------------------------------
// Fused LIF layer scan. One block per batch; 1024 threads, ONE column each.
// rec gathered over active rows (ascending k, sequential adds -> bit-exact).
// slist holds byte offsets (k<<12); load address = slist_val | (tid*4).
// ---------------------------------------------------------------------------

#define LIF_LOAD(Xa, Xb, Xc, Xd, Xe, Xf, Xg, Xh, cidx)                        \
    {                                                                         \
        const int4 ka_ = *(const int4*)&slist[(cidx) << 3];                   \
        const int4 kb_ = *(const int4*)&slist[(((cidx) << 3) + 4)];           \
        Xa = *(const float*)(Rb + (unsigned)(ka_.x | tid4));                  \
        Xb = *(const float*)(Rb + (unsigned)(ka_.y | tid4));                  \
        Xc = *(const float*)(Rb + (unsigned)(ka_.z | tid4));                  \
        Xd = *(const float*)(Rb + (unsigned)(ka_.w | tid4));                  \
        Xe = *(const float*)(Rb + (unsigned)(kb_.x | tid4));                  \
        Xf = *(const float*)(Rb + (unsigned)(kb_.y | tid4));                  \
        Xg = *(const float*)(Rb + (unsigned)(kb_.z | tid4));                  \
        Xh = *(const float*)(Rb + (unsigned)(kb_.w | tid4));                  \
    }

#define LIF_SUM(Xa, Xb, Xc, Xd, Xe, Xf, Xg, Xh)                               \
    {                                                                         \
        a0 += Xa; a0 += Xb; a0 += Xc; a0 += Xd;                               \
        a0 += Xe; a0 += Xf; a0 += Xg; a0 += Xh;                               \
    }

__global__ __launch_bounds__(1024) void lif_scan(
    const float* __restrict__ hbuf,  // [B,T,H]
    const float* __restrict__ R,     // [H,H]
    float* __restrict__ s_out,       // [B,T,H]
    float* __restrict__ v_out)       // [B,T,H]
{
    __shared__ __align__(16) int slist[SNN_H];     // active-row BYTE offsets (ascending k)
    __shared__ int wtot[16];                       // per-wave spike counts
    __shared__ int sn;                             // total active count

    const int tid = threadIdx.x;                   // == column j
    const int tid4 = tid << 2;                     // byte offset of column
    const int b = blockIdx.x;
    const int wv = tid >> 6;                       // wave 0..15
    const int lane = tid & 63;
    const char* __restrict__ Rb = (const char*)R;

    float cur = 0.f, pot = 0.f;

    if (tid == 0) sn = 0;
    __syncthreads();

    const float* hrow = hbuf + (size_t)b * SNN_T * SNN_H + tid;
    float*       srow = s_out + (size_t)b * SNN_T * SNN_H + tid;
    float*       vrow = v_out + (size_t)b * SNN_T * SNN_H + tid;

    for (int t = 0; t < SNN_T; ++t) {
        const float hv = *hrow;                    // issue early, hide under rec
        hrow += SNN_H;

        // ---- rec from active rows of R (spikes t-1), ascending k ----
        const int n = sn;
        float a0 = 0.f;
        int i = 0;
        const int nc = n >> 3;                     // full 8-chunks
        if (nc > 0) {
            float A0, A1, A2, A3, A4, A5, A6, A7;
            float B0, B1, B2, B3, B4, B5, B6, B7;
            LIF_LOAD(A0, A1, A2, A3, A4, A5, A6, A7, 0);
            int c = 1;
            for (; c + 1 < nc; c += 2) {
                LIF_LOAD(B0, B1, B2, B3, B4, B5, B6, B7, c);
                LIF_SUM(A0, A1, A2, A3, A4, A5, A6, A7);       // chunk c-1
                LIF_LOAD(A0, A1, A2, A3, A4, A5, A6, A7, c + 1);
                LIF_SUM(B0, B1, B2, B3, B4, B5, B6, B7);       // chunk c
            }
            if (c < nc) {
                LIF_LOAD(B0, B1, B2, B3, B4, B5, B6, B7, c);
                LIF_SUM(A0, A1, A2, A3, A4, A5, A6, A7);       // chunk c-1
                LIF_SUM(B0, B1, B2, B3, B4, B5, B6, B7);       // chunk c
            } else {
                LIF_SUM(A0, A1, A2, A3, A4, A5, A6, A7);       // last chunk
            }
            i = nc << 3;
        }
        for (; i < n; ++i)
            a0 += *(const float*)(Rb + (unsigned)(slist[i] | tid4));

        // ---- spike from pot(t-1), state update (same forms as round 0) ----
        const bool p = (pot - 1.0f) > 0.0f;
        const float s = p ? 1.0f : 0.0f;
        cur = fmaf(ALPHA, cur, hv) + a0;
        pot = fmaf(BETA, pot, cur) * (1.0f - s);

        *srow = s;
        *vrow = pot;
        srow += SNN_H; vrow += SNN_H;

        // ---- build next step's active list, ASCENDING k ----
        const unsigned long long m = __ballot(p);
        const unsigned long long lt = (1ull << lane) - 1ull;
        const int lpre = __popcll(m & lt);
        if (lane == 0) wtot[wv] = __popcll(m);
        __syncthreads();   // wtot ready AND all threads done reading slist
        int off = lpre;
        #pragma unroll
        for (int q = 0; q < 15; ++q)
            if (q < wv) off += wtot[q];
        if (p) slist[off] = tid << 12;             // byte offset of row k = tid
        if (tid == 0) {
            int stot = 0;
            #pragma unroll
            for (int q = 0; q < 16; ++q) stot += wtot[q];
            sn = stot;
        }
        __syncthreads();   // slist/sn ready for step t+1
    }
}

// ---------------------------------------------------------------------------
// Readout GEMM: h3[row, o] = sum_k s2[row, k] * Wout[k, o].
// Thread per row, 8 accumulators; Wout index is uniform -> scalar loads.
// Per-output ascending-k fmaf chain (exact, same order as before).
// ---------------------------------------------------------------------------
__global__ __launch_bounds__(256) void readout_gemm(
    const float* __restrict__ s2in, const float* __restrict__ Wout,
    float* __restrict__ h3)
{
    const int row = blockIdx.x * 256 + threadIdx.x;
    const float* srow = s2in + (size_t)row * SNN_H;
    float acc[8] = {};
    for (int k = 0; k < SNN_H; k += 4) {
        const float4 s = *(const float4*)&srow[k];
        const float sv[4] = {s.x, s.y, s.z, s.w};
        #pragma unroll
        for (int kk = 0; kk < 4; ++kk)
            #pragma unroll
            for (int o = 0; o < 8; ++o)
                acc[o] = fmaf(sv[kk], Wout[(size_t)(k + kk) * SNN_O + o], acc[o]);
    }
    float* hp = h3 + (size_t)row * SNN_O;
    *(float4*)hp = make_float4(acc[0], acc[1], acc[2], acc[3]);
    *(float4*)(hp + 4) = make_float4(acc[4], acc[5], acc[6], acc[7]);
}

// ---------------------------------------------------------------------------
// Readout linear scan. (unchanged)
// ---------------------------------------------------------------------------
__global__ __launch_bounds__(256) void readout_scan(
    const float* __restrict__ h3, float* __restrict__ out)
{
    const int gid = blockIdx.x * 256 + threadIdx.x;  // 2048 = B*O
    const int b = gid >> 3;
    const int o = gid & 7;
    float c = 0.f, p = 0.f;
    out[((size_t)b * (SNN_T + 1) + 0) * SNN_O + o] = 0.f;
    for (int t = 0; t < SNN_T; ++t) {
        c = fmaf(ALPHA, c, h3[((size_t)b * SNN_T + t) * SNN_O + o]);
        p = fmaf(BETA, p, c);
        out[((size_t)b * (SNN_T + 1) + t + 1) * SNN_O + o] = p;
    }
}

// ---------------------------------------------------------------------------
extern "C" void kernel_launch(void* const* d_in, const int* in_sizes, int n_in,
                              void* d_out, int out_size, void* d_ws, size_t ws_size,
                              hipStream_t stream)
{
    const float* X    = (const float*)d_in[0];  // [B,T,F]
    const float* W0   = (const float*)d_in[1];  // [F,H]
    const float* W1   = (const float*)d_in[2];  // [H,H]
    const float* R0   = (const float*)d_in[3];  // [H,H]
    const float* R1   = (const float*)d_in[4];  // [H,H]
    const float* Wout = (const float*)d_in[5];  // [H,O]

    const size_t BT_H = (size_t)SNN_B * SNN_T * SNN_H;  // 26,214,400
    float* out = (float*)d_out;                          // [B,T+1,O]
    float* s1  = out + (size_t)SNN_B * (SNN_T + 1) * SNN_O;
    float* s2  = s1 + BT_H;
    float* v1  = s2 + BT_H;
    float* v2  = v1 + BT_H;

    float* ws   = (float*)d_ws;
    float* hbuf = ws;                       // [B*T*H] (h1, then reused for h2)
    float* h3   = hbuf + BT_H;              // [B*T*O]

    const int M = SNN_B * SNN_T;  // 25600

    // h1 = X @ W0
    gemm_f32<<<dim3(SNN_H / 128, M / 128), 256, 0, stream>>>(X, W0, hbuf, M, SNN_H, SNN_F);

    // layer-1 fused scan (100 steps in one launch)
    lif_scan<<<SNN_B, 1024, 0, stream>>>(hbuf, R0, s1, v1);

    // h2 = s1 @ W1 (reuse hbuf)
    gemm_f32<<<dim3(SNN_H / 128, M / 128), 256, 0, stream>>>(s1, W1, hbuf, M, SNN_H, SNN_H);

    // layer-2 fused scan
    lif_scan<<<SNN_B, 1024, 0, stream>>>(hbuf, R1, s2, v2);

    // readout
    readout_gemm<<<M / 256, 256, 0, stream>>>(s2, Wout, h3);
    readout_scan<<<(SNN_B * SNN_O) / 256, 256, 0, stream>>>(h3, out);
}